// Round 13
// baseline (194.342 us; speedup 1.0000x reference)
//
#include <hip/hip_runtime.h>
#include <hip/hip_bf16.h>
#include <stdint.h>
#include <math.h>

#define BATCH 4
#define SEQ   2048
#define NHEAD 16
#define DIM   1024
#define DKV   64
#define MTOT  (BATCH*SEQ)   // 8192

typedef __attribute__((ext_vector_type(8))) short  bf16x8;
typedef __attribute__((ext_vector_type(4))) float  f32x4;
typedef unsigned short u16;
typedef unsigned int   u32;
typedef __attribute__((ext_vector_type(2))) u32 u32x2;
typedef __attribute__((ext_vector_type(4))) u32 u32x4;

// 0.125 (1/sqrt(dk)) * log2(e): folded into Q so attention runs exp2-domain.
#define QSCALE 0.18033688011112042f
#define THR    8.0f

__device__ __forceinline__ u16 f2bf(float f) {
  __hip_bfloat16 h = __float2bfloat16(f);
  u16 r;
  __builtin_memcpy(&r, &h, 2);
  return r;
}
__device__ __forceinline__ u32 pkbf(float lo, float hi) {
  __hip_bfloat162 h = __float22bfloat162_rn(float2{lo, hi});
  u32 r;
  __builtin_memcpy(&r, &h, 4);
  return r;
}

__device__ __forceinline__ void gload_lds16(const void* g, void* l) {
  __builtin_amdgcn_global_load_lds((u32 __attribute__((address_space(1)))*)(g),
                                   (u32 __attribute__((address_space(3)))*)(l),
                                   16, 0, 0);
}

// ---------------- fused conversions (one launch) ----------------

__global__ void k_cvt_all(const float* __restrict__ q,
                          const float* __restrict__ Wq, const float* __restrict__ Wk,
                          const float* __restrict__ Wv, const float* __restrict__ Wo,
                          u16* __restrict__ qb, u16* __restrict__ wqt, u16* __restrict__ wkt,
                          u16* __restrict__ wvt, u16* __restrict__ wot) {
  int bid = blockIdx.x;
  if (bid < 8192) {
    const int i = (bid * 256 + threadIdx.x) * 4;
    float4 v = *(const float4*)(q + i);
    u32x2 o;
    o[0] = pkbf(v.x, v.y); o[1] = pkbf(v.z, v.w);
    *(u32x2*)(qb + i) = o;
    return;
  }
  bid -= 8192;
  const int which = bid >> 12;               // 0..3
  const int idx = (bid & 4095) * 256 + threadIdx.x;
  if (which < 3) {
    const float* w = (which == 0) ? Wq : (which == 1) ? Wk : Wv;
    u16* wt        = (which == 0) ? wqt : (which == 1) ? wkt : wvt;
    const int n = idx >> 10, d = idx & 1023;
    wt[idx] = f2bf(w[((n >> 6) << 16) + (d << 6) + (n & 63)]);
  } else {
    const int e = idx >> 10, hv = idx & 1023;
    wot[idx] = f2bf(Wo[(hv << 10) + e]);
  }
}

// ---------------- pipelined 256x128 GEMM (4-phase, counted vmcnt) ----------------
// MODE: 0 = bf16 C[m][n], 1 = f32 C[m][n], 2 = bf16 * QSCALE,
// MODE 3 = bf16 V^T [n][m'] with PV k-order permutation baked into m:
//          within each 32-run (m = 32a+16s+4g+r) store at m' = 32a+8g+4s+r.

template<int MODE>
__device__ __forceinline__ void gemm2(u16* __restrict__ sm,
                                      const u16* __restrict__ A, const u16* __restrict__ Bt,
                                      void* __restrict__ Cp, int m0, int n0) {
  const int tid = threadIdx.x, wid = tid >> 6, lane = tid & 63;
  const int g = lane >> 4, li = lane & 15;
  const int wm = wid >> 1, wn = wid & 1;

  const int c0 = wid * 128 + lane, c1 = c0 + 64;
  const int s0 = (c0 * 8) ^ (((c0 >> 3) & 7) << 3);
  const int s1 = (c1 * 8) ^ (((c1 >> 3) & 7) << 3);
  const int cB = tid;
  const int sB = (cB * 8) ^ (((cB >> 3) & 7) << 3);
  const u16* As0 = A  + (size_t)(m0 + (s0 >> 5)) * DIM + (s0 & 31);
  const u16* As1 = A  + (size_t)(m0 + (s1 >> 5)) * DIM + (s1 & 31);
  const u16* Bs  = Bt + (size_t)(n0 + (sB >> 5)) * DIM + (sB & 31);
  u16* dA0 = sm + wid * 1024;
  u16* dA1 = sm + wid * 1024 + 512;
  u16* dB  = sm + 32768 + wid * 512;

#define SA2(t, ks, tb) do { \
    gload_lds16(As0 + (t) * 64 + (ks) * 32, dA0 + (tb) * 16384 + (ks) * 8192); \
    gload_lds16(As1 + (t) * 64 + (ks) * 32, dA1 + (tb) * 16384 + (ks) * 8192); } while (0)
#define SB2(t, ks, tb) \
    gload_lds16(Bs + (t) * 64 + (ks) * 32, dB + (tb) * 8192 + (ks) * 4096)

  const int vx = ((li >> 1) & 7) << 3;
  const int a_rd = (((wm * 64 + li) * 32) + g * 8) ^ vx;
  const int b_rd = (((wn * 64 + li) * 32) + g * 8) ^ vx;

  f32x4 acc[4][4] = {};

  SA2(0, 0, 0); SB2(0, 0, 0);
  SA2(0, 1, 0); SB2(0, 1, 0);
  SA2(1, 0, 1); SB2(1, 0, 1);
  asm volatile("s_waitcnt vmcnt(6)" ::: "memory");
  __builtin_amdgcn_s_barrier();

#pragma unroll 2
  for (int kt = 0; kt < 16; ++kt) {
    const int cur = kt & 1, t1 = (kt + 1) & 15, t2 = (kt + 2) & 15;
    const u16* pa = sm + cur * 16384 + a_rd;
    const u16* pb = sm + 32768 + cur * 8192 + b_rd;
    bf16x8 af[2], bfq[4];

#pragma unroll
    for (int j = 0; j < 4; ++j) bfq[j] = *(const bf16x8*)(pb + j * 512);
    af[0] = *(const bf16x8*)(pa);
    af[1] = *(const bf16x8*)(pa + 512);
    SA2(t1, 1, cur ^ 1);
    __builtin_amdgcn_s_barrier();
    __builtin_amdgcn_s_setprio(1);
#pragma unroll
    for (int i = 0; i < 2; ++i)
#pragma unroll
      for (int j = 0; j < 4; ++j)
        acc[i][j] = __builtin_amdgcn_mfma_f32_16x16x32_bf16(af[i], bfq[j], acc[i][j], 0, 0, 0);
    __builtin_amdgcn_s_setprio(0);
    __builtin_amdgcn_s_barrier();

    af[0] = *(const bf16x8*)(pa + 2 * 512);
    af[1] = *(const bf16x8*)(pa + 3 * 512);
    SB2(t1, 1, cur ^ 1);
    __builtin_amdgcn_s_barrier();
    __builtin_amdgcn_s_setprio(1);
#pragma unroll
    for (int i = 0; i < 2; ++i)
#pragma unroll
      for (int j = 0; j < 4; ++j)
        acc[i + 2][j] = __builtin_amdgcn_mfma_f32_16x16x32_bf16(af[i], bfq[j], acc[i + 2][j], 0, 0, 0);
    __builtin_amdgcn_s_setprio(0);
    asm volatile("s_waitcnt vmcnt(3)" ::: "memory");
    __builtin_amdgcn_s_barrier();

#pragma unroll
    for (int j = 0; j < 4; ++j) bfq[j] = *(const bf16x8*)(pb + 4096 + j * 512);
    af[0] = *(const bf16x8*)(pa + 8192);
    af[1] = *(const bf16x8*)(pa + 8192 + 512);
    SA2(t2, 0, cur);
    __builtin_amdgcn_s_barrier();
    __builtin_amdgcn_s_setprio(1);
#pragma unroll
    for (int i = 0; i < 2; ++i)
#pragma unroll
      for (int j = 0; j < 4; ++j)
        acc[i][j] = __builtin_amdgcn_mfma_f32_16x16x32_bf16(af[i], bfq[j], acc[i][j], 0, 0, 0);
    __builtin_amdgcn_s_setprio(0);
    __builtin_amdgcn_s_barrier();

    af[0] = *(const bf16x8*)(pa + 8192 + 2 * 512);
    af[1] = *(const bf16x8*)(pa + 8192 + 3 * 512);
    SB2(t2, 0, cur);
    __builtin_amdgcn_s_barrier();
    __builtin_amdgcn_s_setprio(1);
#pragma unroll
    for (int i = 0; i < 2; ++i)
#pragma unroll
      for (int j = 0; j < 4; ++j)
        acc[i + 2][j] = __builtin_amdgcn_mfma_f32_16x16x32_bf16(af[i], bfq[j], acc[i + 2][j], 0, 0, 0);
    __builtin_amdgcn_s_setprio(0);
    asm volatile("s_waitcnt vmcnt(3)" ::: "memory");
    __builtin_amdgcn_s_barrier();
  }
#undef SA2
#undef SB2

#pragma unroll
  for (int i = 0; i < 4; ++i)
#pragma unroll
    for (int j = 0; j < 4; ++j) {
      const int col = n0 + wn * 64 + j * 16 + li;
      if (MODE == 3) {
        const size_t rowb = (size_t)(m0 + wm * 64 + i * 16 + g * 4) + 4 * g - 12 * (i & 1);
        u32x2 w;
        w[0] = pkbf(acc[i][j][0], acc[i][j][1]);
        w[1] = pkbf(acc[i][j][2], acc[i][j][3]);
        *(u32x2*)((u16*)Cp + (size_t)col * MTOT + rowb) = w;
      } else if (MODE == 1) {
#pragma unroll
        for (int r = 0; r < 4; ++r) {
          const size_t row = (size_t)(m0 + wm * 64 + i * 16 + g * 4 + r);
          ((float*)Cp)[row * DIM + col] = acc[i][j][r];
        }
      } else {
#pragma unroll
        for (int r = 0; r < 4; ++r) {
          const size_t row = (size_t)(m0 + wm * 64 + i * 16 + g * 4 + r);
          float v = acc[i][j][r];
          if (MODE == 2) v *= QSCALE;
          ((u16*)Cp)[row * DIM + col] = f2bf(v);
        }
      }
    }
}

__global__ __launch_bounds__(512, 2)
void k_gemm_qkv2(const u16* __restrict__ A, const u16* __restrict__ wq,
                 const u16* __restrict__ wk, const u16* __restrict__ wv,
                 u16* __restrict__ Qo, u16* __restrict__ Ko, u16* __restrict__ Vto) {
  __shared__ u16 sm[49152];
  const int m0 = blockIdx.x * 256;
  const int yt = blockIdx.y;
  const int wsel = yt >> 3;
  const int n0 = (yt & 7) * 128;
  if (wsel == 0)      gemm2<2>(sm, A, wq, Qo,  m0, n0);
  else if (wsel == 1) gemm2<0>(sm, A, wk, Ko,  m0, n0);
  else                gemm2<3>(sm, A, wv, Vto, m0, n0);
}

__global__ __launch_bounds__(512, 2)
void k_gemm_out2(const u16* __restrict__ A, const u16* __restrict__ Bt, float* __restrict__ C) {
  __shared__ u16 sm[49152];
  gemm2<1>(sm, A, Bt, C, blockIdx.x * 256, blockIdx.y * 128);
}

// ---------------- flash attention (16x16, 32 q-rows/wave, 4-wave blocks) ----------------
// Same per-wave structure as round 12 (MFMA-folded softmax sub, defer-max, cvt_pk,
// ones-MFMA row-sum) but 256-thread blocks: QB=128, grid 1024 = 4 blocks/CU.
// Halves the barrier-convoy width (4 waves vs 8) and doubles independent blocks
// per CU — attacks the 36%-of-50%-cap occupancy gap. Staging: thread covers
// chunks p*256+tid (p=0,1), row = p*32 + wid*8 + r8; swizzle term unchanged.
// 1D grid, id mod 8 = bh mod 8 -> (b,h) XCD-grouped, K/V L2-resident.

#define KB 64
#define NT (SEQ/KB)

__global__ __launch_bounds__(256, 4)
void k_attn(const u16* __restrict__ Q, const u16* __restrict__ K,
            const u16* __restrict__ Vt, u16* __restrict__ O) {
  const int id = blockIdx.x;
  const int bh = id & 63, qt = id >> 6;
  const int b = bh >> 4, h = bh & 15;
  const int q0 = qt * 128;
  const int tid = threadIdx.x, wid = tid >> 6, lane = tid & 63;
  const int g = lane >> 4, li = lane & 15;

  __shared__ u16 kl[2][KB * 64];
  __shared__ u16 vl[2][KB * 64];

  const size_t rb = (size_t)b * SEQ;
  const int hc = h * DKV;

  bf16x8 qf[2][2];
#pragma unroll
  for (int u = 0; u < 2; ++u) {
    const u16* qp = Q + (rb + q0 + wid * 32 + u * 16 + li) * DIM + hc;
    qf[u][0] = *(const bf16x8*)(qp + g * 8);
    qf[u][1] = *(const bf16x8*)(qp + 32 + g * 8);
  }

  bf16x8 ones;
#pragma unroll
  for (int j = 0; j < 8; ++j) ones[j] = (short)0x3F80;

  float mrun[2] = {0.f, 0.f};
  float lrun[2] = {0.f, 0.f};
  f32x4 o[2][4] = {};

  const int r8   = lane >> 3;
  const int swz  = ((lane & 7) ^ r8) * 8;
  const int sr0  = wid * 8 + r8;        // p=0 row
  const int sr1  = 32 + wid * 8 + r8;   // p=1 row

  gload_lds16(K  + (rb + sr0) * DIM + hc + swz,          &kl[0][wid * 512]);
  gload_lds16(K  + (rb + sr1) * DIM + hc + swz,          &kl[0][2048 + wid * 512]);
  gload_lds16(Vt + (size_t)(hc + sr0) * MTOT + rb + swz, &vl[0][wid * 512]);
  gload_lds16(Vt + (size_t)(hc + sr1) * MTOT + rb + swz, &vl[0][2048 + wid * 512]);

#pragma unroll 2
  for (int it = 0; it < NT; ++it) {
    const int cur = it & 1;
    __syncthreads();

    if (it + 1 < NT) {
      const int n1 = (it + 1) * KB;
      gload_lds16(K  + (rb + n1 + sr0) * DIM + hc + swz,          &kl[cur ^ 1][wid * 512]);
      gload_lds16(K  + (rb + n1 + sr1) * DIM + hc + swz,          &kl[cur ^ 1][2048 + wid * 512]);
      gload_lds16(Vt + (size_t)(hc + sr0) * MTOT + rb + n1 + swz, &vl[cur ^ 1][wid * 512]);
      gload_lds16(Vt + (size_t)(hc + sr1) * MTOT + rb + n1 + swz, &vl[cur ^ 1][2048 + wid * 512]);
    }

    const u16* kb = kl[cur];
    const u16* vb = vl[cur];
    const int sw = (li & 7) << 3;

    // S^T - m = K·Q^T + (-mrun) : softmax sub folded into the MFMA C-operand
    const float mn0 = -mrun[0], mn1 = -mrun[1];
    f32x4 s[2][4];
    __builtin_amdgcn_s_setprio(1);
#pragma unroll
    for (int t = 0; t < 4; ++t) {
      const int row = t * 16 + li;
      bf16x8 kf0 = *(const bf16x8*)(kb + row * 64 + ((g * 8) ^ sw));
      bf16x8 kf1 = *(const bf16x8*)(kb + row * 64 + ((32 + g * 8) ^ sw));
      f32x4 z0 = {mn0, mn0, mn0, mn0};
      z0 = __builtin_amdgcn_mfma_f32_16x16x32_bf16(kf0, qf[0][0], z0, 0, 0, 0);
      z0 = __builtin_amdgcn_mfma_f32_16x16x32_bf16(kf1, qf[0][1], z0, 0, 0, 0);
      s[0][t] = z0;
      f32x4 z1 = {mn1, mn1, mn1, mn1};
      z1 = __builtin_amdgcn_mfma_f32_16x16x32_bf16(kf0, qf[1][0], z1, 0, 0, 0);
      z1 = __builtin_amdgcn_mfma_f32_16x16x32_bf16(kf1, qf[1][1], z1, 0, 0, 0);
      s[1][t] = z1;
    }
    __builtin_amdgcn_s_setprio(0);

    // online softmax per row-tile: s already holds S - m
    bf16x8 pa[2][2];
#pragma unroll
    for (int u = 0; u < 2; ++u) {
      f32x4 mv = __builtin_elementwise_max(__builtin_elementwise_max(s[u][0], s[u][1]),
                                           __builtin_elementwise_max(s[u][2], s[u][3]));
      const float lmax = fmaxf(fmaxf(mv[0], mv[1]), fmaxf(mv[2], mv[3]));
      if (__any(lmax > THR)) {              // rare rescale branch
        float d = fmaxf(lmax, __shfl_xor(lmax, 16));
        d = fmaxf(d, __shfl_xor(d, 32));
        d = fmaxf(d, 0.f);                  // never lower the running max
        const float corr = __builtin_amdgcn_exp2f(-d);
        mrun[u] += d;
        lrun[u] *= corr;
#pragma unroll
        for (int t = 0; t < 4; ++t) {
          o[u][t] *= corr;
          s[u][t] -= d;
        }
      }
#pragma unroll
      for (int t = 0; t < 4; ++t)
#pragma unroll
        for (int r = 0; r < 4; ++r)
          s[u][t][r] = __builtin_amdgcn_exp2f(s[u][t][r]);   // no sub in common path

#pragma unroll
      for (int hh = 0; hh < 2; ++hh) {
        u32x4 pw;
        pw[0] = pkbf(s[u][2 * hh][0],     s[u][2 * hh][1]);
        pw[1] = pkbf(s[u][2 * hh][2],     s[u][2 * hh][3]);
        pw[2] = pkbf(s[u][2 * hh + 1][0], s[u][2 * hh + 1][1]);
        pw[3] = pkbf(s[u][2 * hh + 1][2], s[u][2 * hh + 1][3]);
        pa[u][hh] = __builtin_bit_cast(bf16x8, pw);
      }

      f32x4 zs = {};
      zs = __builtin_amdgcn_mfma_f32_16x16x32_bf16(ones, pa[u][0], zs, 0, 0, 0);
      zs = __builtin_amdgcn_mfma_f32_16x16x32_bf16(ones, pa[u][1], zs, 0, 0, 0);
      lrun[u] += zs[0];
    }

    // O^T += V^T·P^T : each V-fragment read feeds both u row-tiles
    __builtin_amdgcn_s_setprio(1);
#pragma unroll
    for (int t = 0; t < 4; ++t) {
      const int row = t * 16 + li;
#pragma unroll
      for (int hh = 0; hh < 2; ++hh) {
        bf16x8 vf = *(const bf16x8*)(vb + row * 64 + ((hh * 32 + g * 8) ^ sw));
#pragma unroll
        for (int u = 0; u < 2; ++u)
          o[u][t] = __builtin_amdgcn_mfma_f32_16x16x32_bf16(vf, pa[u][hh], o[u][t], 0, 0, 0);
      }
    }
    __builtin_amdgcn_s_setprio(0);
  }

#pragma unroll
  for (int u = 0; u < 2; ++u) {
    const float inv = 1.0f / lrun[u];
    const size_t qrow = rb + q0 + wid * 32 + u * 16 + li;
#pragma unroll
    for (int t = 0; t < 4; ++t) {
      u32x2 w;
      w[0] = pkbf(o[u][t][0] * inv, o[u][t][1] * inv);
      w[1] = pkbf(o[u][t][2] * inv, o[u][t][3] * inv);
      *(u32x2*)(O + qrow * DIM + hc + t * 16 + 4 * g) = w;
    }
  }
}

// ---------------- launch ----------------

extern "C" void kernel_launch(void* const* d_in, const int* in_sizes, int n_in,
                              void* d_out, int out_size, void* d_ws, size_t ws_size,
                              hipStream_t stream) {
  (void)in_sizes; (void)n_in; (void)out_size; (void)ws_size;
  const float* q  = (const float*)d_in[0];
  const float* Wq = (const float*)d_in[1];
  const float* Wk = (const float*)d_in[2];
  const float* Wv = (const float*)d_in[3];
  const float* Wo = (const float*)d_in[4];
  float* out = (float*)d_out;

  char* p = (char*)d_ws;
  u16* qb  = (u16*)p; p += (size_t)MTOT * DIM * 2;
  u16* wqt = (u16*)p; p += (size_t)DIM * DIM * 2;
  u16* wkt = (u16*)p; p += (size_t)DIM * DIM * 2;
  u16* wvt = (u16*)p; p += (size_t)DIM * DIM * 2;
  u16* wot = (u16*)p; p += (size_t)DIM * DIM * 2;
  u16* Qb  = (u16*)p; p += (size_t)MTOT * DIM * 2;
  u16* Kb  = (u16*)p; p += (size_t)MTOT * DIM * 2;
  u16* Vtb = (u16*)p; p += (size_t)MTOT * DIM * 2;
  u16* Hb  = Qb;   // heads reuse Q buffer (attn reads its Q tile to regs before writing same region)

  k_cvt_all<<<8192 + 4 * 4096, 256, 0, stream>>>(q, Wq, Wk, Wv, Wo, qb, wqt, wkt, wvt, wot);

  k_gemm_qkv2<<<dim3(MTOT / 256, 24), 512, 0, stream>>>(qb, wqt, wkt, wvt, Qb, Kb, Vtb);
  k_attn<<<(SEQ / 128) * BATCH * NHEAD, 256, 0, stream>>>(Qb, Kb, Vtb, Hb);
  k_gemm_out2<<<dim3(MTOT / 256, DIM / 128), 512, 0, stream>>>(Hb, wot, out);
}

// Round 14
// 192.502 us; speedup vs baseline: 1.0096x; 1.0096x over previous
//
#include <hip/hip_runtime.h>
#include <hip/hip_bf16.h>
#include <stdint.h>
#include <math.h>

#define BATCH 4
#define SEQ   2048
#define NHEAD 16
#define DIM   1024
#define DKV   64
#define MTOT  (BATCH*SEQ)   // 8192

typedef __attribute__((ext_vector_type(8))) short  bf16x8;
typedef __attribute__((ext_vector_type(4))) float  f32x4;
typedef unsigned short u16;
typedef unsigned int   u32;
typedef __attribute__((ext_vector_type(2))) u32 u32x2;
typedef __attribute__((ext_vector_type(4))) u32 u32x4;

// 0.125 (1/sqrt(dk)) * log2(e): folded into Q so attention runs exp2-domain.
#define QSCALE 0.18033688011112042f
#define THR    8.0f

__device__ __forceinline__ u16 f2bf(float f) {
  __hip_bfloat16 h = __float2bfloat16(f);
  u16 r;
  __builtin_memcpy(&r, &h, 2);
  return r;
}
__device__ __forceinline__ u32 pkbf(float lo, float hi) {
  __hip_bfloat162 h = __float22bfloat162_rn(float2{lo, hi});
  u32 r;
  __builtin_memcpy(&r, &h, 4);
  return r;
}

__device__ __forceinline__ void gload_lds16(const void* g, void* l) {
  __builtin_amdgcn_global_load_lds((u32 __attribute__((address_space(1)))*)(g),
                                   (u32 __attribute__((address_space(3)))*)(l),
                                   16, 0, 0);
}

// ---------------- fused conversions (one launch) ----------------

__global__ void k_cvt_all(const float* __restrict__ q,
                          const float* __restrict__ Wq, const float* __restrict__ Wk,
                          const float* __restrict__ Wv, const float* __restrict__ Wo,
                          u16* __restrict__ qb, u16* __restrict__ wqt, u16* __restrict__ wkt,
                          u16* __restrict__ wvt, u16* __restrict__ wot) {
  int bid = blockIdx.x;
  if (bid < 8192) {
    const int i = (bid * 256 + threadIdx.x) * 4;
    float4 v = *(const float4*)(q + i);
    u32x2 o;
    o[0] = pkbf(v.x, v.y); o[1] = pkbf(v.z, v.w);
    *(u32x2*)(qb + i) = o;
    return;
  }
  bid -= 8192;
  const int which = bid >> 12;               // 0..3
  const int idx = (bid & 4095) * 256 + threadIdx.x;
  if (which < 3) {
    const float* w = (which == 0) ? Wq : (which == 1) ? Wk : Wv;
    u16* wt        = (which == 0) ? wqt : (which == 1) ? wkt : wvt;
    const int n = idx >> 10, d = idx & 1023;
    wt[idx] = f2bf(w[((n >> 6) << 16) + (d << 6) + (n & 63)]);
  } else {
    const int e = idx >> 10, hv = idx & 1023;
    wot[idx] = f2bf(Wo[(hv << 10) + e]);
  }
}

// ---------------- pipelined 256x128 GEMM (4-phase, counted vmcnt) ----------------
// MODE: 0 = bf16 C[m][n], 1 = f32 C[m][n], 2 = bf16 * QSCALE,
// MODE 3 = bf16 V^T [n][m'] with PV k-order permutation baked into m:
//          within each 32-run (m = 32a+16s+4g+r) store at m' = 32a+8g+4s+r.

template<int MODE>
__device__ __forceinline__ void gemm2(u16* __restrict__ sm,
                                      const u16* __restrict__ A, const u16* __restrict__ Bt,
                                      void* __restrict__ Cp, int m0, int n0) {
  const int tid = threadIdx.x, wid = tid >> 6, lane = tid & 63;
  const int g = lane >> 4, li = lane & 15;
  const int wm = wid >> 1, wn = wid & 1;

  const int c0 = wid * 128 + lane, c1 = c0 + 64;
  const int s0 = (c0 * 8) ^ (((c0 >> 3) & 7) << 3);
  const int s1 = (c1 * 8) ^ (((c1 >> 3) & 7) << 3);
  const int cB = tid;
  const int sB = (cB * 8) ^ (((cB >> 3) & 7) << 3);
  const u16* As0 = A  + (size_t)(m0 + (s0 >> 5)) * DIM + (s0 & 31);
  const u16* As1 = A  + (size_t)(m0 + (s1 >> 5)) * DIM + (s1 & 31);
  const u16* Bs  = Bt + (size_t)(n0 + (sB >> 5)) * DIM + (sB & 31);
  u16* dA0 = sm + wid * 1024;
  u16* dA1 = sm + wid * 1024 + 512;
  u16* dB  = sm + 32768 + wid * 512;

#define SA2(t, ks, tb) do { \
    gload_lds16(As0 + (t) * 64 + (ks) * 32, dA0 + (tb) * 16384 + (ks) * 8192); \
    gload_lds16(As1 + (t) * 64 + (ks) * 32, dA1 + (tb) * 16384 + (ks) * 8192); } while (0)
#define SB2(t, ks, tb) \
    gload_lds16(Bs + (t) * 64 + (ks) * 32, dB + (tb) * 8192 + (ks) * 4096)

  const int vx = ((li >> 1) & 7) << 3;
  const int a_rd = (((wm * 64 + li) * 32) + g * 8) ^ vx;
  const int b_rd = (((wn * 64 + li) * 32) + g * 8) ^ vx;

  f32x4 acc[4][4] = {};

  SA2(0, 0, 0); SB2(0, 0, 0);
  SA2(0, 1, 0); SB2(0, 1, 0);
  SA2(1, 0, 1); SB2(1, 0, 1);
  asm volatile("s_waitcnt vmcnt(6)" ::: "memory");
  __builtin_amdgcn_s_barrier();

#pragma unroll 2
  for (int kt = 0; kt < 16; ++kt) {
    const int cur = kt & 1, t1 = (kt + 1) & 15, t2 = (kt + 2) & 15;
    const u16* pa = sm + cur * 16384 + a_rd;
    const u16* pb = sm + 32768 + cur * 8192 + b_rd;
    bf16x8 af[2], bfq[4];

#pragma unroll
    for (int j = 0; j < 4; ++j) bfq[j] = *(const bf16x8*)(pb + j * 512);
    af[0] = *(const bf16x8*)(pa);
    af[1] = *(const bf16x8*)(pa + 512);
    SA2(t1, 1, cur ^ 1);
    __builtin_amdgcn_s_barrier();
    __builtin_amdgcn_s_setprio(1);
#pragma unroll
    for (int i = 0; i < 2; ++i)
#pragma unroll
      for (int j = 0; j < 4; ++j)
        acc[i][j] = __builtin_amdgcn_mfma_f32_16x16x32_bf16(af[i], bfq[j], acc[i][j], 0, 0, 0);
    __builtin_amdgcn_s_setprio(0);
    __builtin_amdgcn_s_barrier();

    af[0] = *(const bf16x8*)(pa + 2 * 512);
    af[1] = *(const bf16x8*)(pa + 3 * 512);
    SB2(t1, 1, cur ^ 1);
    __builtin_amdgcn_s_barrier();
    __builtin_amdgcn_s_setprio(1);
#pragma unroll
    for (int i = 0; i < 2; ++i)
#pragma unroll
      for (int j = 0; j < 4; ++j)
        acc[i + 2][j] = __builtin_amdgcn_mfma_f32_16x16x32_bf16(af[i], bfq[j], acc[i + 2][j], 0, 0, 0);
    __builtin_amdgcn_s_setprio(0);
    asm volatile("s_waitcnt vmcnt(3)" ::: "memory");
    __builtin_amdgcn_s_barrier();

#pragma unroll
    for (int j = 0; j < 4; ++j) bfq[j] = *(const bf16x8*)(pb + 4096 + j * 512);
    af[0] = *(const bf16x8*)(pa + 8192);
    af[1] = *(const bf16x8*)(pa + 8192 + 512);
    SA2(t2, 0, cur);
    __builtin_amdgcn_s_barrier();
    __builtin_amdgcn_s_setprio(1);
#pragma unroll
    for (int i = 0; i < 2; ++i)
#pragma unroll
      for (int j = 0; j < 4; ++j)
        acc[i][j] = __builtin_amdgcn_mfma_f32_16x16x32_bf16(af[i], bfq[j], acc[i][j], 0, 0, 0);
    __builtin_amdgcn_s_setprio(0);
    __builtin_amdgcn_s_barrier();

    af[0] = *(const bf16x8*)(pa + 8192 + 2 * 512);
    af[1] = *(const bf16x8*)(pa + 8192 + 3 * 512);
    SB2(t2, 0, cur);
    __builtin_amdgcn_s_barrier();
    __builtin_amdgcn_s_setprio(1);
#pragma unroll
    for (int i = 0; i < 2; ++i)
#pragma unroll
      for (int j = 0; j < 4; ++j)
        acc[i + 2][j] = __builtin_amdgcn_mfma_f32_16x16x32_bf16(af[i], bfq[j], acc[i + 2][j], 0, 0, 0);
    __builtin_amdgcn_s_setprio(0);
    asm volatile("s_waitcnt vmcnt(3)" ::: "memory");
    __builtin_amdgcn_s_barrier();
  }
#undef SA2
#undef SB2

#pragma unroll
  for (int i = 0; i < 4; ++i)
#pragma unroll
    for (int j = 0; j < 4; ++j) {
      const int col = n0 + wn * 64 + j * 16 + li;
      if (MODE == 3) {
        const size_t rowb = (size_t)(m0 + wm * 64 + i * 16 + g * 4) + 4 * g - 12 * (i & 1);
        u32x2 w;
        w[0] = pkbf(acc[i][j][0], acc[i][j][1]);
        w[1] = pkbf(acc[i][j][2], acc[i][j][3]);
        *(u32x2*)((u16*)Cp + (size_t)col * MTOT + rowb) = w;
      } else if (MODE == 1) {
#pragma unroll
        for (int r = 0; r < 4; ++r) {
          const size_t row = (size_t)(m0 + wm * 64 + i * 16 + g * 4 + r);
          ((float*)Cp)[row * DIM + col] = acc[i][j][r];
        }
      } else {
#pragma unroll
        for (int r = 0; r < 4; ++r) {
          const size_t row = (size_t)(m0 + wm * 64 + i * 16 + g * 4 + r);
          float v = acc[i][j][r];
          if (MODE == 2) v *= QSCALE;
          ((u16*)Cp)[row * DIM + col] = f2bf(v);
        }
      }
    }
}

__global__ __launch_bounds__(512, 2)
void k_gemm_qkv2(const u16* __restrict__ A, const u16* __restrict__ wq,
                 const u16* __restrict__ wk, const u16* __restrict__ wv,
                 u16* __restrict__ Qo, u16* __restrict__ Ko, u16* __restrict__ Vto) {
  __shared__ u16 sm[49152];
  const int m0 = blockIdx.x * 256;
  const int yt = blockIdx.y;
  const int wsel = yt >> 3;
  const int n0 = (yt & 7) * 128;
  if (wsel == 0)      gemm2<2>(sm, A, wq, Qo,  m0, n0);
  else if (wsel == 1) gemm2<0>(sm, A, wk, Ko,  m0, n0);
  else                gemm2<3>(sm, A, wv, Vto, m0, n0);
}

__global__ __launch_bounds__(512, 2)
void k_gemm_out2(const u16* __restrict__ A, const u16* __restrict__ Bt, float* __restrict__ C) {
  __shared__ u16 sm[49152];
  gemm2<1>(sm, A, Bt, C, blockIdx.x * 256, blockIdx.y * 128);
}

// ---------------- flash attention (16x16, 32 q-rows/wave, MFMA-folded softmax sub) ----------------
// Round-12 configuration (best measured). 512 threads = 8 waves, QB=256.
// QK^T accumulator initialized to -mrun -> s = S - m from the matrix pipe;
// common defer-max path has zero subs. mrun starts 0 (first-tile rescale corrects).
// 1D grid of 512 blocks, id mod 8 = bh mod 8 -> (b,h) XCD-grouped, K/V L2-resident.

#define KB 64
#define NT (SEQ/KB)

__global__ __launch_bounds__(512, 4)
void k_attn(const u16* __restrict__ Q, const u16* __restrict__ K,
            const u16* __restrict__ Vt, u16* __restrict__ O) {
  const int id = blockIdx.x;
  const int bh = id & 63, qt = id >> 6;
  const int b = bh >> 4, h = bh & 15;
  const int q0 = qt * 256;
  const int tid = threadIdx.x, wid = tid >> 6, lane = tid & 63;
  const int g = lane >> 4, li = lane & 15;

  __shared__ u16 kl[2][KB * 64];
  __shared__ u16 vl[2][KB * 64];

  const size_t rb = (size_t)b * SEQ;
  const int hc = h * DKV;

  bf16x8 qf[2][2];
#pragma unroll
  for (int u = 0; u < 2; ++u) {
    const u16* qp = Q + (rb + q0 + wid * 32 + u * 16 + li) * DIM + hc;
    qf[u][0] = *(const bf16x8*)(qp + g * 8);
    qf[u][1] = *(const bf16x8*)(qp + 32 + g * 8);
  }

  bf16x8 ones;
#pragma unroll
  for (int j = 0; j < 8; ++j) ones[j] = (short)0x3F80;

  float mrun[2] = {0.f, 0.f};
  float lrun[2] = {0.f, 0.f};
  f32x4 o[2][4] = {};

  const int r8   = lane >> 3;
  const int swz  = ((lane & 7) ^ r8) * 8;
  const int srow = wid * 8 + r8;

  gload_lds16(K  + (rb + srow) * DIM + hc + swz,          &kl[0][wid * 512]);
  gload_lds16(Vt + (size_t)(hc + srow) * MTOT + rb + swz, &vl[0][wid * 512]);

#pragma unroll 2
  for (int it = 0; it < NT; ++it) {
    const int cur = it & 1;
    __syncthreads();

    if (it + 1 < NT) {
      const int n1 = (it + 1) * KB;
      gload_lds16(K  + (rb + n1 + srow) * DIM + hc + swz,          &kl[cur ^ 1][wid * 512]);
      gload_lds16(Vt + (size_t)(hc + srow) * MTOT + rb + n1 + swz, &vl[cur ^ 1][wid * 512]);
    }

    const u16* kb = kl[cur];
    const u16* vb = vl[cur];
    const int sw = (li & 7) << 3;

    // S^T - m = K·Q^T + (-mrun) : softmax sub folded into the MFMA C-operand
    const float mn0 = -mrun[0], mn1 = -mrun[1];
    f32x4 s[2][4];
    __builtin_amdgcn_s_setprio(1);
#pragma unroll
    for (int t = 0; t < 4; ++t) {
      const int row = t * 16 + li;
      bf16x8 kf0 = *(const bf16x8*)(kb + row * 64 + ((g * 8) ^ sw));
      bf16x8 kf1 = *(const bf16x8*)(kb + row * 64 + ((32 + g * 8) ^ sw));
      f32x4 z0 = {mn0, mn0, mn0, mn0};
      z0 = __builtin_amdgcn_mfma_f32_16x16x32_bf16(kf0, qf[0][0], z0, 0, 0, 0);
      z0 = __builtin_amdgcn_mfma_f32_16x16x32_bf16(kf1, qf[0][1], z0, 0, 0, 0);
      s[0][t] = z0;
      f32x4 z1 = {mn1, mn1, mn1, mn1};
      z1 = __builtin_amdgcn_mfma_f32_16x16x32_bf16(kf0, qf[1][0], z1, 0, 0, 0);
      z1 = __builtin_amdgcn_mfma_f32_16x16x32_bf16(kf1, qf[1][1], z1, 0, 0, 0);
      s[1][t] = z1;
    }
    __builtin_amdgcn_s_setprio(0);

    // online softmax per row-tile: s already holds S - m
    bf16x8 pa[2][2];
#pragma unroll
    for (int u = 0; u < 2; ++u) {
      f32x4 mv = __builtin_elementwise_max(__builtin_elementwise_max(s[u][0], s[u][1]),
                                           __builtin_elementwise_max(s[u][2], s[u][3]));
      const float lmax = fmaxf(fmaxf(mv[0], mv[1]), fmaxf(mv[2], mv[3]));
      if (__any(lmax > THR)) {              // rare rescale branch
        float d = fmaxf(lmax, __shfl_xor(lmax, 16));
        d = fmaxf(d, __shfl_xor(d, 32));
        d = fmaxf(d, 0.f);                  // never lower the running max
        const float corr = __builtin_amdgcn_exp2f(-d);
        mrun[u] += d;
        lrun[u] *= corr;
#pragma unroll
        for (int t = 0; t < 4; ++t) {
          o[u][t] *= corr;
          s[u][t] -= d;
        }
      }
#pragma unroll
      for (int t = 0; t < 4; ++t)
#pragma unroll
        for (int r = 0; r < 4; ++r)
          s[u][t][r] = __builtin_amdgcn_exp2f(s[u][t][r]);   // no sub in common path

#pragma unroll
      for (int hh = 0; hh < 2; ++hh) {
        u32x4 pw;
        pw[0] = pkbf(s[u][2 * hh][0],     s[u][2 * hh][1]);
        pw[1] = pkbf(s[u][2 * hh][2],     s[u][2 * hh][3]);
        pw[2] = pkbf(s[u][2 * hh + 1][0], s[u][2 * hh + 1][1]);
        pw[3] = pkbf(s[u][2 * hh + 1][2], s[u][2 * hh + 1][3]);
        pa[u][hh] = __builtin_bit_cast(bf16x8, pw);
      }

      f32x4 zs = {};
      zs = __builtin_amdgcn_mfma_f32_16x16x32_bf16(ones, pa[u][0], zs, 0, 0, 0);
      zs = __builtin_amdgcn_mfma_f32_16x16x32_bf16(ones, pa[u][1], zs, 0, 0, 0);
      lrun[u] += zs[0];
    }

    // O^T += V^T·P^T : each V-fragment read feeds both u row-tiles
    __builtin_amdgcn_s_setprio(1);
#pragma unroll
    for (int t = 0; t < 4; ++t) {
      const int row = t * 16 + li;
#pragma unroll
      for (int hh = 0; hh < 2; ++hh) {
        bf16x8 vf = *(const bf16x8*)(vb + row * 64 + ((hh * 32 + g * 8) ^ sw));
#pragma unroll
        for (int u = 0; u < 2; ++u)
          o[u][t] = __builtin_amdgcn_mfma_f32_16x16x32_bf16(vf, pa[u][hh], o[u][t], 0, 0, 0);
      }
    }
    __builtin_amdgcn_s_setprio(0);
  }

#pragma unroll
  for (int u = 0; u < 2; ++u) {
    const float inv = 1.0f / lrun[u];
    const size_t qrow = rb + q0 + wid * 32 + u * 16 + li;
#pragma unroll
    for (int t = 0; t < 4; ++t) {
      u32x2 w;
      w[0] = pkbf(o[u][t][0] * inv, o[u][t][1] * inv);
      w[1] = pkbf(o[u][t][2] * inv, o[u][t][3] * inv);
      *(u32x2*)(O + qrow * DIM + hc + t * 16 + 4 * g) = w;
    }
  }
}

// ---------------- launch ----------------

extern "C" void kernel_launch(void* const* d_in, const int* in_sizes, int n_in,
                              void* d_out, int out_size, void* d_ws, size_t ws_size,
                              hipStream_t stream) {
  (void)in_sizes; (void)n_in; (void)out_size; (void)ws_size;
  const float* q  = (const float*)d_in[0];
  const float* Wq = (const float*)d_in[1];
  const float* Wk = (const float*)d_in[2];
  const float* Wv = (const float*)d_in[3];
  const float* Wo = (const float*)d_in[4];
  float* out = (float*)d_out;

  char* p = (char*)d_ws;
  u16* qb  = (u16*)p; p += (size_t)MTOT * DIM * 2;
  u16* wqt = (u16*)p; p += (size_t)DIM * DIM * 2;
  u16* wkt = (u16*)p; p += (size_t)DIM * DIM * 2;
  u16* wvt = (u16*)p; p += (size_t)DIM * DIM * 2;
  u16* wot = (u16*)p; p += (size_t)DIM * DIM * 2;
  u16* Qb  = (u16*)p; p += (size_t)MTOT * DIM * 2;
  u16* Kb  = (u16*)p; p += (size_t)MTOT * DIM * 2;
  u16* Vtb = (u16*)p; p += (size_t)MTOT * DIM * 2;
  u16* Hb  = Qb;   // heads reuse Q buffer (attn reads its Q tile to regs before writing same region)

  k_cvt_all<<<8192 + 4 * 4096, 256, 0, stream>>>(q, Wq, Wk, Wv, Wo, qb, wqt, wkt, wvt, wot);

  k_gemm_qkv2<<<dim3(MTOT / 256, 24), 512, 0, stream>>>(qb, wqt, wkt, wvt, Qb, Kb, Vtb);
  k_attn<<<(SEQ / 256) * BATCH * NHEAD, 512, 0, stream>>>(Qb, Kb, Vtb, Hb);
  k_gemm_out2<<<dim3(MTOT / 256, DIM / 128), 512, 0, stream>>>(Hb, wot, out);
}